// Round 9
// baseline (259.658 us; speedup 1.0000x reference)
//
#include <hip/hip_runtime.h>
#include <math.h>

#define BB   16
#define RR   4096
#define NC   80          // foreground classes
#define KK   300
#define DD   100
#define CCAP 256         // per-(image,class) candidate cap (expected ~118, sigma ~11)
#define CAP  16384       // per-image kept-candidate cap (expected ~8800)
#define LCAP 48          // per-(block,class) local cap in kernel A
#define NW   4           // 4*64 = 256 bitmask words (N <= CCAP = 256)
#define PAD  256
#define TPB  4           // percls tasks (waves) per block
#define HBINS 1280       // topd histogram bins (used: 1128)
#define HPT   5          // bins per scan-thread (1280/256)
#define BIN0  0x7A99u    // (0x3D4CCCCD >> 15): bin of score==0.05f

typedef unsigned long long ull;

// wave-local "barrier": drain LDS ops + compiler memory fence (single-wave tasks)
__device__ __forceinline__ void wsync() {
    asm volatile("s_waitcnt lgkmcnt(0)" ::: "memory");
}

__device__ __forceinline__ float4 decode_box(const float4 pr, const float4 rg) {
    float dx = rg.x / 10.0f;
    float dy = rg.y / 10.0f;
    float dw = fminf(rg.z / 5.0f, 4.135166556742356f);
    float dh = fminf(rg.w / 5.0f, 4.135166556742356f);
    float w  = pr.z - pr.x + 1.0f;
    float h  = pr.w - pr.y + 1.0f;
    float cx = pr.x + 0.5f * w;
    float cy = pr.y + 0.5f * h;
    float pcx = dx * w + cx;
    float pcy = dy * h + cy;
    float pw  = expf(dw) * w;
    float ph  = expf(dh) * h;
    float x1 = pcx - 0.5f * pw;
    float y1 = pcy - 0.5f * ph;
    float x2 = pcx + 0.5f * pw - 1.0f;
    float y2 = pcy + 0.5f * ph - 1.0f;
    x1 = fminf(fmaxf(x1, 0.0f), 1332.0f);
    y1 = fminf(fmaxf(y1, 0.0f), 799.0f);
    x2 = fminf(fmaxf(x2, 0.0f), 1332.0f);
    y2 = fminf(fmaxf(y2, 0.0f), 799.0f);
    return make_float4(x1, y1, x2, y2);
}

// ---- Kernel A: register-resident softmax + block-aggregated emit (unchanged) ----
__global__ __launch_bounds__(256) void softmax_cand_kernel(
        const float* __restrict__ logits,
        ull*         __restrict__ cand2,     // [BB*NC][CCAP]
        int*         __restrict__ cls_cnt) { // [BB*NC]
    __shared__ float tile[256 * 81];
    __shared__ ull   lbuf[NC * LCAP];
    __shared__ int   lhist[NC];
    __shared__ int   gbase[NC];

    const int tid  = threadIdx.x;
    const int row0 = blockIdx.x * 256;
    const int b    = blockIdx.x >> 4;

    for (int i = tid; i < NC; i += 256) lhist[i] = 0;

    const float4* src = (const float4*)(logits + (size_t)row0 * 81);
    float4*       dst = (float4*)tile;
    for (int i = tid; i < 5184; i += 256) dst[i] = src[i];
    __syncthreads();

    float v[81];
    #pragma unroll
    for (int c = 0; c < 81; ++c) v[c] = tile[tid * 81 + c];

    float m = -1e30f;
    #pragma unroll
    for (int c = 0; c < 81; ++c) m = fmaxf(m, v[c]);

    float s = 0.0f;
    #pragma unroll
    for (int c = 0; c < 81; ++c) { float e = expf(v[c] - m); v[c] = e; s += e; }

    const unsigned rlow = (unsigned)((row0 + tid) & 4095);
    #pragma unroll
    for (int c = 1; c < 81; ++c) {
        float p = v[c] / s;
        if (p > 0.05f) {
            int ci  = c - 1;
            int pos = atomicAdd(&lhist[ci], 1);
            if (pos < LCAP)
                lbuf[ci * LCAP + pos] =
                    ((ull)__float_as_uint(p) << 32) | (unsigned)(~rlow);
        }
    }
    __syncthreads();

    if (tid < NC) {
        int h = lhist[tid]; if (h > LCAP) h = LCAP;
        gbase[tid] = atomicAdd(&cls_cnt[b * NC + tid], h);
    }
    __syncthreads();

    for (int idx = tid; idx < NC * LCAP; idx += 256) {
        int ci = idx / LCAP, j = idx - ci * LCAP;
        int h  = lhist[ci]; if (h > LCAP) h = LCAP;
        if (j < h) {
            int pos = gbase[ci] + j;
            if (pos < CCAP)
                cand2[(size_t)(b * NC + ci) * CCAP + pos] = lbuf[idx];
        }
    }
}

// ---- Kernel B: 4 waves/block, one wave per (image,class); register bitonic sort ----
__global__ __launch_bounds__(256) void percls_kernel(
        const ull*   __restrict__ cand2,
        const int*   __restrict__ cls_cnt,
        const float* __restrict__ box_reg,
        const float* __restrict__ proposals,
        ull*         __restrict__ img_keys,   // [BB][CAP]
        unsigned*    __restrict__ img_meta,   // [BB][CAP]  (ci<<12 | r)
        int*         __restrict__ g_cnt) {    // [BB]
    #pragma clang fp contract(off)
    __shared__ float4 bxyS[TPB][PAD];   // 16 KB

    const int wave = threadIdx.x >> 6;
    const int lane = threadIdx.x & 63;
    const int bid  = blockIdx.x * TPB + wave;   // 0..1279
    const int b    = bid / NC;
    const int ci   = bid % NC;

    int M = cls_cnt[bid]; if (M > CCAP) M = CCAP;

    // load 4 keys/lane: slot i = lane + 64q
    ull r[4];
    #pragma unroll
    for (int q = 0; q < 4; ++q) {
        int i = lane + 64 * q;
        r[q] = (i < M) ? cand2[(size_t)bid * CCAP + i] : 0ULL;
    }

    // 256-slot bitonic sort, descending, fully in registers (shfl_xor network)
    #pragma unroll
    for (int k = 2; k <= 256; k <<= 1) {
        #pragma unroll
        for (int j = k >> 1; j > 0; j >>= 1) {
            if (j >= 64) {
                const int qj = j >> 6;          // 1 or 2
                #pragma unroll
                for (int q = 0; q < 4; ++q) {
                    if ((q & qj) == 0 && (q + qj) < 4) {
                        int i0 = lane + 64 * q;
                        bool desc = ((i0 & k) == 0);
                        ull x = r[q], y = r[q + qj];
                        bool sw = desc ? (x < y) : (x > y);
                        if (sw) { r[q] = y; r[q + qj] = x; }
                    }
                }
            } else {
                #pragma unroll
                for (int q = 0; q < 4; ++q) {
                    int i0 = lane + 64 * q;
                    bool desc  = ((i0 & k) == 0);
                    bool lower = ((lane & j) == 0);
                    ull pv = __shfl_xor(r[q], j);
                    bool take = (desc == lower) ? (pv > r[q]) : (pv < r[q]);
                    if (take) r[q] = pv;
                }
            }
        }
    }

    const int N = M;   // M <= 256 < KK

    // decode own rows (rank k2 = 64t + lane lives in r[t]); boxes to LDS + regs
    float4 myb[4]; float mya[4];
    #pragma unroll
    for (int t = 0; t < 4; ++t) {
        const int k2 = 64 * t + lane;
        if (k2 < N) {
            unsigned rr = ~(unsigned)(r[t] & 0xFFFFFFFFu);
            size_t n = (size_t)b * RR + rr;
            const float4 pr = *(const float4*)(proposals + n * 4);
            const float4 rg = *(const float4*)(box_reg + n * 324 + (size_t)(ci + 1) * 4);
            float4 bb = decode_box(pr, rg);
            myb[t] = bb;
            mya[t] = (bb.z - bb.x + 1.0f) * (bb.w - bb.y + 1.0f);
            bxyS[wave][k2] = bb;
        } else {
            myb[t] = make_float4(0.0f, 0.0f, 0.0f, 0.0f);
            mya[t] = 0.0f;
            bxyS[wave][k2] = make_float4(0.0f, 0.0f, 0.0f, 0.0f);
        }
    }
    wsync();

    // keep mask (wave-uniform), one bit per candidate (<N only)
    ull keepw[NW];
    #pragma unroll
    for (int w = 0; w < NW; ++w) {
        int lo = w * 64;
        keepw[w] = (N >= lo + 64) ? ~0ULL : (N <= lo ? 0ULL : ((1ULL << (N - lo)) - 1ULL));
    }

    #pragma unroll
    for (int t = 0; t < NW; ++t) {
        if (t * 64 >= N) break;
        const int i = t * 64 + lane;
        const float4 a   = myb[t];
        const float  aar = mya[t];
        ull sup[NW];
        #pragma unroll
        for (int w = 0; w < NW; ++w) {
            ull mword = 0ULL;
            if (w >= t && w * 64 < N) {
                int jlo = w * 64; if (jlo < i + 1) jlo = i + 1;
                int jhi = w * 64 + 64; if (jhi > N) jhi = N;
                if (jlo < jhi) {
                    float4 nb = bxyS[wave][jlo];
                    for (int j = jlo; j < jhi; ++j) {
                        float4 cb = nb;
                        int jn = (j + 1 < jhi) ? j + 1 : j;
                        nb = bxyS[wave][jn];                 // prefetch next
                        float ba  = (cb.z - cb.x + 1.0f) * (cb.w - cb.y + 1.0f);
                        float ltx = fmaxf(a.x, cb.x);
                        float lty = fmaxf(a.y, cb.y);
                        float rbx = fminf(a.z, cb.z);
                        float rby = fminf(a.w, cb.w);
                        float iw  = fmaxf(rbx - ltx + 1.0f, 0.0f);
                        float ih  = fmaxf(rby - lty + 1.0f, 0.0f);
                        float inter = iw * ih;
                        float iou   = inter / ((aar + ba) - inter);
                        if (iou > 0.5f) mword |= 1ULL << (j - w * 64);
                    }
                }
            }
            sup[w] = mword;
        }
        // only leaders with a non-empty suppression row matter
        ull rowany = 0ULL;
        #pragma unroll
        for (int w = 0; w < NW; ++w) rowany |= sup[w];
        const ull act = __ballot(rowany != 0ULL);

        ull mloop = keepw[t] & act;
        while (mloop) {
            int l = __builtin_ctzll(mloop);
            if ((keepw[t] >> l) & 1ULL) {
                #pragma unroll
                for (int w = 0; w < NW; ++w) {
                    if (w >= t && w * 64 < N)
                        keepw[w] &= ~__shfl(sup[w], l);
                }
            }
            ull below = (l >= 63) ? ~0ULL : ((1ULL << (l + 1)) - 1ULL);
            mloop = keepw[t] & act & ~below;
        }
    }

    // append: ONE global atomic per wave, popcll-rank offsets
    int total = 0;
    #pragma unroll
    for (int w = 0; w < NW; ++w) total += __popcll(keepw[w]);
    int base0 = 0;
    if (lane == 0) base0 = atomicAdd(&g_cnt[b], total);
    base0 = __shfl(base0, 0);

    int acc = 0;
    #pragma unroll
    for (int w = 0; w < NW; ++w) {
        if (w * 64 < N) {
            const ull km = keepw[w];
            const int k2 = w * 64 + lane;
            if ((km >> lane) & 1ULL) {
                int rank = __popcll(km & ((1ULL << lane) - 1ULL));
                int pos  = base0 + acc + rank;
                if (pos < CAP) {
                    unsigned rr = ~(unsigned)(r[w] & 0xFFFFFFFFu);
                    unsigned fi = (unsigned)(ci * KK + k2);
                    img_keys[(size_t)b * CAP + pos] =
                        (r[w] & 0xFFFFFFFF00000000ULL) | (unsigned)(~fi);
                    img_meta[(size_t)b * CAP + pos] = ((unsigned)ci << 12) | (rr & 4095u);
                }
            }
            acc += __popcll(km);
        }
    }
}

// ---- Kernel C: histogram select + single-wave register sort + emit ----
__global__ __launch_bounds__(1024) void topd_kernel(
        const ull*      __restrict__ img_keys,
        const unsigned* __restrict__ img_meta,
        const int*      __restrict__ g_cnt,
        const float*    __restrict__ box_reg,
        const float*    __restrict__ proposals,
        float*          __restrict__ out) {
    __shared__ int  hist[HBINS];
    __shared__ int  suf[256];
    __shared__ ull  pk[256];
    __shared__ int  ps[256];
    __shared__ int  sh_cnt, sh_tb;

    const int b   = blockIdx.x;
    const int tid = threadIdx.x;
    int M = g_cnt[b]; if (M > CAP) M = CAP;
    const ull* kp = img_keys + (size_t)b * CAP;

    for (int i = tid; i < HBINS; i += 1024) hist[i] = 0;
    if (tid == 0) { sh_cnt = 0; sh_tb = 0; }
    __syncthreads();

    // 1) histogram on score-bits >> 15
    for (int i = tid; i < M; i += 1024) {
        unsigned k = (unsigned)(kp[i] >> 32);
        int bin = (int)((k >> 15) - BIN0);
        bin = (bin < 0) ? 0 : (bin >= HBINS ? HBINS - 1 : bin);
        atomicAdd(&hist[bin], 1);
    }
    __syncthreads();

    // 2) suffix scan over 256 chunks
    int tot = 0;
    if (tid < 256) {
        #pragma unroll
        for (int r = 0; r < HPT; ++r) tot += hist[tid * HPT + r];
        suf[tid] = tot;
    }
    __syncthreads();
    for (int off = 1; off < 256; off <<= 1) {
        int add = 0;
        if (tid < 256 && tid + off < 256) add = suf[tid + off];
        __syncthreads();
        if (tid < 256) suf[tid] += add;
        __syncthreads();
    }
    // 3) threshold bin
    if (tid < 256) {
        int cum = suf[tid] - tot;
        #pragma unroll
        for (int jj = HPT - 1; jj >= 0; --jj) {
            int j    = tid * HPT + jj;
            int prev = cum;
            cum += hist[j];
            if (cum >= DD && prev < DD) sh_tb = j;
        }
    }
    __syncthreads();
    const unsigned keyLo = ((unsigned)sh_tb + BIN0) << 15;

    // 4) gather (expected ~100-130 entries)
    for (int i = tid; i < M; i += 1024) {
        ull key = kp[i];
        if ((unsigned)(key >> 32) >= keyLo) {
            int p = atomicAdd(&sh_cnt, 1);
            if (p < 256) { pk[p] = key; ps[p] = i; }
        }
    }
    __syncthreads();

    // 5+6) single wave: register bitonic sort (carrying slot) + emit
    if (tid < 64) {
        const int lane  = tid;
        int ngath = sh_cnt; if (ngath > 256) ngath = 256;

        ull k4[4]; int s4[4];
        #pragma unroll
        for (int q = 0; q < 4; ++q) {
            int i = lane + 64 * q;
            bool vld = (i < ngath);
            k4[q] = vld ? pk[i] : 0ULL;
            s4[q] = vld ? ps[i] : -1;
        }

        #pragma unroll
        for (int k = 2; k <= 256; k <<= 1) {
            #pragma unroll
            for (int j = k >> 1; j > 0; j >>= 1) {
                if (j >= 64) {
                    const int qj = j >> 6;
                    #pragma unroll
                    for (int q = 0; q < 4; ++q) {
                        if ((q & qj) == 0 && (q + qj) < 4) {
                            int i0 = lane + 64 * q;
                            bool desc = ((i0 & k) == 0);
                            ull x = k4[q], y = k4[q + qj];
                            bool sw = desc ? (x < y) : (x > y);
                            if (sw) {
                                k4[q] = y; k4[q + qj] = x;
                                int t = s4[q]; s4[q] = s4[q + qj]; s4[q + qj] = t;
                            }
                        }
                    }
                } else {
                    #pragma unroll
                    for (int q = 0; q < 4; ++q) {
                        int i0 = lane + 64 * q;
                        bool desc  = ((i0 & k) == 0);
                        bool lower = ((lane & j) == 0);
                        ull pv = __shfl_xor(k4[q], j);
                        int sv = __shfl_xor(s4[q], j);
                        bool take = (desc == lower) ? (pv > k4[q]) : (pv < k4[q]);
                        if (take) { k4[q] = pv; s4[q] = sv; }
                    }
                }
            }
        }

        #pragma unroll
        for (int q = 0; q < 2; ++q) {          // positions 0..127 cover DD=100
            int p = lane + 64 * q;
            if (p < DD) {
                float s; float4 bb; int label;
                if (p < ngath) {
                    ull key = k4[q];
                    unsigned fi   = ~(unsigned)(key & 0xFFFFFFFFu);
                    unsigned meta = img_meta[(size_t)b * CAP + s4[q]];
                    unsigned rr   = meta & 4095u;
                    unsigned ci   = meta >> 12;
                    s  = __uint_as_float((unsigned)(key >> 32));
                    size_t n = (size_t)b * RR + rr;
                    const float4 pr = *(const float4*)(proposals + n * 4);
                    const float4 rg = *(const float4*)(box_reg + n * 324 + (size_t)(ci + 1) * 4);
                    bb = decode_box(pr, rg);
                    label = (int)(fi / KK) + 1;
                } else {
                    s = -1.0f; bb = make_float4(0.0f, 0.0f, 0.0f, 0.0f); label = 0;
                }
                *(float4*)(out + (size_t)(b * DD + p) * 4) = bb;
                out[(size_t)BB * DD * 4 + b * DD + p] = s;
                out[(size_t)BB * DD * 4 + BB * DD + b * DD + p] = (float)label;
            }
        }
    }
}

extern "C" void kernel_launch(void* const* d_in, const int* in_sizes, int n_in,
                              void* d_out, int out_size, void* d_ws, size_t ws_size,
                              hipStream_t stream) {
    const float* logits    = (const float*)d_in[0];   // [B*R, 81]
    const float* box_reg   = (const float*)d_in[1];   // [B*R, 324]
    const float* proposals = (const float*)d_in[2];   // [B*R, 4]
    float* out = (float*)d_out;

    char* ws = (char*)d_ws;
    int*      cls_cnt  = (int*)ws;                    //     5,120 B
    int*      g_cnt    = (int*)(ws + 5120);           //        64 B
    ull*      cand2    = (ull*)(ws + 5184);           // 2,621,440 B (1280*256*8)
    ull*      img_keys = (ull*)(ws + 2626624);        // 2,097,152 B
    unsigned* img_meta = (unsigned*)(ws + 4723776);   // 1,048,576 B

    hipMemsetAsync(ws, 0, 5184, stream);
    softmax_cand_kernel<<<(BB * RR) / 256, 256, 0, stream>>>(logits, cand2, cls_cnt);
    percls_kernel<<<(BB * NC) / TPB, 256, 0, stream>>>(cand2, cls_cnt, box_reg, proposals,
                                                       img_keys, img_meta, g_cnt);
    topd_kernel<<<BB, 1024, 0, stream>>>(img_keys, img_meta, g_cnt,
                                         box_reg, proposals, out);
}

// Round 10
// 239.553 us; speedup vs baseline: 1.0839x; 1.0839x over previous
//
#include <hip/hip_runtime.h>
#include <math.h>

#define BB   16
#define RR   4096
#define NC   80          // foreground classes
#define KK   300
#define DD   100
#define CCAP 512         // per-(image,class) candidate cap (expected ~118, sigma ~11)
#define CAP  16384       // per-image kept-candidate cap (expected ~8800)
#define LCAP 48          // per-(block,class) local cap in kernel A
#define NW   5           // 5*64 = 320 >= KK bitmask words
#define PAD  (NW * 64)   // 320 padded box slots
#define TPB  4           // percls tasks (waves) per block
#define HBINS 1280       // histogram bins (used: 1128)
#define HPT   5          // bins per scan-thread (1280/256)
#define BIN0  0x7A99u    // (0x3D4CCCCD >> 15): bin of score==0.05f
#define GCAP 512         // per-image gathered top-candidate cap (expected ~100-130)
#define SPLIT 8          // blocks per image in topd phases C1/C2

typedef unsigned long long ull;

// wave-local "barrier": drain LDS ops + compiler memory fence (single-wave tasks)
__device__ __forceinline__ void wsync() {
    asm volatile("s_waitcnt lgkmcnt(0)" ::: "memory");
}

__device__ __forceinline__ float4 decode_box(const float4 pr, const float4 rg) {
    float dx = rg.x / 10.0f;
    float dy = rg.y / 10.0f;
    float dw = fminf(rg.z / 5.0f, 4.135166556742356f);
    float dh = fminf(rg.w / 5.0f, 4.135166556742356f);
    float w  = pr.z - pr.x + 1.0f;
    float h  = pr.w - pr.y + 1.0f;
    float cx = pr.x + 0.5f * w;
    float cy = pr.y + 0.5f * h;
    float pcx = dx * w + cx;
    float pcy = dy * h + cy;
    float pw  = expf(dw) * w;
    float ph  = expf(dh) * h;
    float x1 = pcx - 0.5f * pw;
    float y1 = pcy - 0.5f * ph;
    float x2 = pcx + 0.5f * pw - 1.0f;
    float y2 = pcy + 0.5f * ph - 1.0f;
    x1 = fminf(fmaxf(x1, 0.0f), 1332.0f);
    y1 = fminf(fmaxf(y1, 0.0f), 799.0f);
    x2 = fminf(fmaxf(x2, 0.0f), 1332.0f);
    y2 = fminf(fmaxf(y2, 0.0f), 799.0f);
    return make_float4(x1, y1, x2, y2);
}

// ---- Kernel A: LDS-staged coalesced softmax + block-aggregated candidate emit ----
__global__ __launch_bounds__(256) void softmax_cand_kernel(
        const float* __restrict__ logits,
        ull*         __restrict__ cand2,     // [BB*NC][CCAP]
        int*         __restrict__ cls_cnt) { // [BB*NC]
    __shared__ float tile[256 * 81];
    __shared__ ull   lbuf[NC * LCAP];
    __shared__ int   lhist[NC];
    __shared__ int   gbase[NC];

    const int tid  = threadIdx.x;
    const int row0 = blockIdx.x * 256;
    const int b    = blockIdx.x >> 4;

    for (int i = tid; i < NC; i += 256) lhist[i] = 0;

    const float4* src = (const float4*)(logits + (size_t)row0 * 81);
    float4*       dst = (float4*)tile;
    for (int i = tid; i < 5184; i += 256) dst[i] = src[i];
    __syncthreads();

    float v[81];
    #pragma unroll
    for (int c = 0; c < 81; ++c) v[c] = tile[tid * 81 + c];

    float m = -1e30f;
    #pragma unroll
    for (int c = 0; c < 81; ++c) m = fmaxf(m, v[c]);

    float s = 0.0f;
    #pragma unroll
    for (int c = 0; c < 81; ++c) { float e = expf(v[c] - m); v[c] = e; s += e; }

    const unsigned rlow = (unsigned)((row0 + tid) & 4095);
    #pragma unroll
    for (int c = 1; c < 81; ++c) {
        float p = v[c] / s;
        if (p > 0.05f) {
            int ci  = c - 1;
            int pos = atomicAdd(&lhist[ci], 1);
            if (pos < LCAP)
                lbuf[ci * LCAP + pos] =
                    ((ull)__float_as_uint(p) << 32) | (unsigned)(~rlow);
        }
    }
    __syncthreads();

    if (tid < NC) {
        int h = lhist[tid]; if (h > LCAP) h = LCAP;
        gbase[tid] = atomicAdd(&cls_cnt[b * NC + tid], h);
    }
    __syncthreads();

    for (int idx = tid; idx < NC * LCAP; idx += 256) {
        int ci = idx / LCAP, j = idx - ci * LCAP;
        int h  = lhist[ci]; if (h > LCAP) h = LCAP;
        if (j < h) {
            int pos = gbase[ci] + j;
            if (pos < CCAP)
                cand2[(size_t)(b * NC + ci) * CCAP + pos] = lbuf[idx];
        }
    }
}

// ---- Kernel B: 4 waves/block, ONE WAVE per (image,class), no block barriers ----
__global__ __launch_bounds__(256) void percls_kernel(
        const ull*   __restrict__ cand2,
        const int*   __restrict__ cls_cnt,
        const float* __restrict__ box_reg,
        const float* __restrict__ proposals,
        ull*         __restrict__ img_keys,   // [BB][CAP]
        unsigned*    __restrict__ img_meta,   // [BB][CAP]  (ci<<12 | r)
        int*         __restrict__ g_cnt) {    // [BB]
    #pragma clang fp contract(off)
    __shared__ ull   keys[TPB][CCAP];
    __shared__ float bx1[TPB][PAD], by1[TPB][PAD],
                     bx2[TPB][PAD], by2[TPB][PAD], bar[TPB][PAD];

    const int wave = threadIdx.x >> 6;
    const int lane = threadIdx.x & 63;
    const int bid  = blockIdx.x * TPB + wave;   // 0..1279
    const int b    = bid / NC;
    const int ci   = bid % NC;

    int M = cls_cnt[bid]; if (M > CCAP) M = CCAP;
    int sortN = 2; while (sortN < M) sortN <<= 1;

    for (int i = lane; i < sortN; i += 64)
        keys[wave][i] = (i < M) ? cand2[(size_t)bid * CCAP + i] : 0ULL;
    wsync();

    for (int k = 2; k <= sortN; k <<= 1) {
        for (int j = k >> 1; j > 0; j >>= 1) {
            for (int i = lane; i < sortN; i += 64) {
                int ixj = i ^ j;
                if (ixj > i) {
                    bool desc = ((i & k) == 0);
                    ull a = keys[wave][i], c = keys[wave][ixj];
                    if (desc ? (a < c) : (a > c)) { keys[wave][i] = c; keys[wave][ixj] = a; }
                }
            }
            wsync();
        }
    }

    const int N = (M < KK) ? M : KK;

    for (int k2 = lane; k2 < PAD; k2 += 64) {
        if (k2 < N) {
            unsigned r = ~(unsigned)(keys[wave][k2] & 0xFFFFFFFFu);
            size_t n = (size_t)b * RR + r;
            const float4 pr = *(const float4*)(proposals + n * 4);
            const float4 rg = *(const float4*)(box_reg + n * 324 + (size_t)(ci + 1) * 4);
            float4 bb = decode_box(pr, rg);
            bx1[wave][k2] = bb.x; by1[wave][k2] = bb.y;
            bx2[wave][k2] = bb.z; by2[wave][k2] = bb.w;
            bar[wave][k2] = (bb.z - bb.x + 1.0f) * (bb.w - bb.y + 1.0f);
        } else {
            bx1[wave][k2] = 0.0f; by1[wave][k2] = 0.0f;
            bx2[wave][k2] = 0.0f; by2[wave][k2] = 0.0f;
            bar[wave][k2] = 0.0f;
        }
    }
    wsync();

    ull keepw[NW];
    #pragma unroll
    for (int w = 0; w < NW; ++w) {
        int lo = w * 64;
        keepw[w] = (N >= lo + 64) ? ~0ULL : (N <= lo ? 0ULL : ((1ULL << (N - lo)) - 1ULL));
    }

    #pragma unroll
    for (int t = 0; t < NW; ++t) {
        if (t * 64 >= N) break;
        const int i = t * 64 + lane;
        const float ax1 = bx1[wave][i], ay1 = by1[wave][i],
                    ax2 = bx2[wave][i], ay2 = by2[wave][i], aar = bar[wave][i];
        ull sup[NW];
        #pragma unroll
        for (int w = 0; w < NW; ++w) {
            ull mword = 0ULL;
            if (w >= t && w * 64 < N) {
                int jlo = w * 64; if (jlo < i + 1) jlo = i + 1;
                int jhi = w * 64 + 64; if (jhi > N) jhi = N;
                for (int j = jlo; j < jhi; ++j) {
                    float ltx = fmaxf(ax1, bx1[wave][j]);
                    float lty = fmaxf(ay1, by1[wave][j]);
                    float rbx = fminf(ax2, bx2[wave][j]);
                    float rby = fminf(ay2, by2[wave][j]);
                    float iw  = fmaxf(rbx - ltx + 1.0f, 0.0f);
                    float ih  = fmaxf(rby - lty + 1.0f, 0.0f);
                    float inter = iw * ih;
                    float iou   = inter / ((aar + bar[wave][j]) - inter);
                    if (iou > 0.5f) mword |= 1ULL << (j - w * 64);
                }
            }
            sup[w] = mword;
        }
        ull rowany = 0ULL;
        #pragma unroll
        for (int w = 0; w < NW; ++w) rowany |= sup[w];
        const ull act = __ballot(rowany != 0ULL);

        ull mloop = keepw[t] & act;
        while (mloop) {
            int l = __builtin_ctzll(mloop);
            if ((keepw[t] >> l) & 1ULL) {
                #pragma unroll
                for (int w = 0; w < NW; ++w) {
                    if (w >= t && w * 64 < N)
                        keepw[w] &= ~__shfl(sup[w], l);
                }
            }
            ull below = (l >= 63) ? ~0ULL : ((1ULL << (l + 1)) - 1ULL);
            mloop = keepw[t] & act & ~below;
        }
    }

    int total = 0;
    #pragma unroll
    for (int w = 0; w < NW; ++w) total += __popcll(keepw[w]);
    int base0 = 0;
    if (lane == 0) base0 = atomicAdd(&g_cnt[b], total);
    base0 = __shfl(base0, 0);

    int acc = 0;
    #pragma unroll
    for (int w = 0; w < NW; ++w) {
        if (w * 64 < N) {
            const ull km = keepw[w];
            const int k2 = w * 64 + lane;
            if ((km >> lane) & 1ULL) {
                int rank = __popcll(km & ((1ULL << lane) - 1ULL));
                int pos  = base0 + acc + rank;
                if (pos < CAP) {
                    unsigned r  = ~(unsigned)(keys[wave][k2] & 0xFFFFFFFFu);
                    unsigned fi = (unsigned)(ci * KK + k2);
                    img_keys[(size_t)b * CAP + pos] =
                        (keys[wave][k2] & 0xFFFFFFFF00000000ULL) | (unsigned)(~fi);
                    img_meta[(size_t)b * CAP + pos] = ((unsigned)ci << 12) | (r & 4095u);
                }
            }
            acc += __popcll(km);
        }
    }
}

// ---- Kernel C1: per-slice histogram -> per-image global hist (128 blocks) ----
__global__ __launch_bounds__(256) void topd_hist_kernel(
        const ull* __restrict__ img_keys,
        const int* __restrict__ g_cnt,
        int*       __restrict__ g_hist) {   // [BB][HBINS]
    __shared__ int lh[HBINS];
    const int b   = blockIdx.x >> 3;
    const int s8  = blockIdx.x & 7;
    const int tid = threadIdx.x;
    int M = g_cnt[b]; if (M > CAP) M = CAP;
    const ull* kp = img_keys + (size_t)b * CAP;

    #pragma unroll
    for (int r = 0; r < HPT; ++r) lh[tid + r * 256] = 0;
    __syncthreads();

    for (int i = s8 * 256 + tid; i < M; i += SPLIT * 256) {
        unsigned k = (unsigned)(kp[i] >> 32);
        int bin = (int)((k >> 15) - BIN0);
        bin = (bin < 0) ? 0 : (bin >= HBINS ? HBINS - 1 : bin);
        atomicAdd(&lh[bin], 1);
    }
    __syncthreads();

    #pragma unroll
    for (int r = 0; r < HPT; ++r) {
        int bin = tid + r * 256;
        int v   = lh[bin];
        if (v) atomicAdd(&g_hist[b * HBINS + bin], v);
    }
}

// ---- Kernel C2: threshold select (redundant per block) + gather (128 blocks) ----
__global__ __launch_bounds__(256) void topd_gather_kernel(
        const ull*      __restrict__ img_keys,
        const unsigned* __restrict__ img_meta,
        const int*      __restrict__ g_cnt,
        const int*      __restrict__ g_hist,
        ull*            __restrict__ gkeys,     // [BB][GCAP]
        unsigned*       __restrict__ gmeta,     // [BB][GCAP]
        int*            __restrict__ g_topcnt) {// [BB]
    __shared__ int suf[256];
    __shared__ int sh_tb;
    const int b   = blockIdx.x >> 3;
    const int s8  = blockIdx.x & 7;
    const int tid = threadIdx.x;
    int M = g_cnt[b]; if (M > CAP) M = CAP;
    const ull* kp = img_keys + (size_t)b * CAP;
    const int* hh = g_hist + b * HBINS;

    if (tid == 0) sh_tb = 0;
    int h[HPT], tot = 0;
    #pragma unroll
    for (int r = 0; r < HPT; ++r) { h[r] = hh[tid * HPT + r]; tot += h[r]; }
    suf[tid] = tot;
    __syncthreads();
    for (int off = 1; off < 256; off <<= 1) {
        int add = (tid + off < 256) ? suf[tid + off] : 0;
        __syncthreads();
        suf[tid] += add;
        __syncthreads();
    }
    {
        int cum = suf[tid] - tot;                 // count strictly above own chunk
        #pragma unroll
        for (int jj = HPT - 1; jj >= 0; --jj) {
            int prev = cum;
            cum += h[jj];
            if (cum >= DD && prev < DD) sh_tb = tid * HPT + jj;
        }
    }
    __syncthreads();
    const unsigned keyLo = ((unsigned)sh_tb + BIN0) << 15;

    for (int i = s8 * 256 + tid; i < M; i += SPLIT * 256) {
        ull key = kp[i];
        if ((unsigned)(key >> 32) >= keyLo) {
            int p = atomicAdd(&g_topcnt[b], 1);
            if (p < GCAP) {
                gkeys[(size_t)b * GCAP + p] = key;
                gmeta[(size_t)b * GCAP + p] = img_meta[(size_t)b * CAP + i];
            }
        }
    }
}

// ---- Kernel C3: sort gathered (~100-130) + re-decode + emit (16 blocks) ----
__global__ __launch_bounds__(256) void topd_emit_kernel(
        const ull*      __restrict__ gkeys,
        const unsigned* __restrict__ gmeta,
        const int*      __restrict__ g_topcnt,
        const float*    __restrict__ box_reg,
        const float*    __restrict__ proposals,
        float*          __restrict__ out) {
    __shared__ ull      pk[GCAP];
    __shared__ unsigned pm[GCAP];
    const int b   = blockIdx.x;
    const int tid = threadIdx.x;
    int ngath = g_topcnt[b]; if (ngath > GCAP) ngath = GCAP;
    const int sortN = (ngath <= 128) ? 128 : (ngath <= 256) ? 256 : GCAP;

    for (int i = tid; i < sortN; i += 256) {
        if (i < ngath) { pk[i] = gkeys[(size_t)b * GCAP + i]; pm[i] = gmeta[(size_t)b * GCAP + i]; }
        else           { pk[i] = 0ULL; pm[i] = 0u; }
    }
    __syncthreads();

    for (int k = 2; k <= sortN; k <<= 1) {
        for (int j = k >> 1; j > 0; j >>= 1) {
            for (int i = tid; i < sortN; i += 256) {
                int ixj = i ^ j;
                if (ixj > i) {
                    bool desc = ((i & k) == 0);
                    ull a = pk[i], c = pk[ixj];
                    if (desc ? (a < c) : (a > c)) {
                        pk[i] = c; pk[ixj] = a;
                        unsigned t = pm[i]; pm[i] = pm[ixj]; pm[ixj] = t;
                    }
                }
            }
            __syncthreads();
        }
    }

    if (tid < DD) {
        float s; float4 bb; int label;
        if (tid < ngath) {
            ull key = pk[tid];
            unsigned fi   = ~(unsigned)(key & 0xFFFFFFFFu);
            unsigned meta = pm[tid];
            unsigned r    = meta & 4095u;
            unsigned ci   = meta >> 12;
            s  = __uint_as_float((unsigned)(key >> 32));
            size_t n = (size_t)b * RR + r;
            const float4 pr = *(const float4*)(proposals + n * 4);
            const float4 rg = *(const float4*)(box_reg + n * 324 + (size_t)(ci + 1) * 4);
            bb = decode_box(pr, rg);
            label = (int)(fi / KK) + 1;
        } else {
            s = -1.0f; bb = make_float4(0.0f, 0.0f, 0.0f, 0.0f); label = 0;
        }
        *(float4*)(out + (size_t)(b * DD + tid) * 4) = bb;
        out[(size_t)BB * DD * 4 + b * DD + tid] = s;
        out[(size_t)BB * DD * 4 + BB * DD + b * DD + tid] = (float)label;
    }
}

extern "C" void kernel_launch(void* const* d_in, const int* in_sizes, int n_in,
                              void* d_out, int out_size, void* d_ws, size_t ws_size,
                              hipStream_t stream) {
    const float* logits    = (const float*)d_in[0];   // [B*R, 81]
    const float* box_reg   = (const float*)d_in[1];   // [B*R, 324]
    const float* proposals = (const float*)d_in[2];   // [B*R, 4]
    float* out = (float*)d_out;

    char* ws = (char*)d_ws;
    int*      cls_cnt  = (int*)ws;                    //      5,120 B
    int*      g_cnt    = (int*)(ws + 5120);           //         64 B
    int*      g_topcnt = (int*)(ws + 5184);           //         64 B
    int*      g_hist   = (int*)(ws + 5248);           //     81,920 B
    ull*      cand2    = (ull*)(ws + 87168);          //  5,242,880 B
    ull*      img_keys = (ull*)(ws + 5330048);        //  2,097,152 B
    unsigned* img_meta = (unsigned*)(ws + 7427200);   //  1,048,576 B
    ull*      gkeys    = (ull*)(ws + 8475776);        //     65,536 B
    unsigned* gmeta    = (unsigned*)(ws + 8541312);   //     32,768 B

    hipMemsetAsync(ws, 0, 87168, stream);             // zero counters + hist
    softmax_cand_kernel<<<(BB * RR) / 256, 256, 0, stream>>>(logits, cand2, cls_cnt);
    percls_kernel<<<(BB * NC) / TPB, 256, 0, stream>>>(cand2, cls_cnt, box_reg, proposals,
                                                       img_keys, img_meta, g_cnt);
    topd_hist_kernel<<<BB * SPLIT, 256, 0, stream>>>(img_keys, g_cnt, g_hist);
    topd_gather_kernel<<<BB * SPLIT, 256, 0, stream>>>(img_keys, img_meta, g_cnt, g_hist,
                                                       gkeys, gmeta, g_topcnt);
    topd_emit_kernel<<<BB, 256, 0, stream>>>(gkeys, gmeta, g_topcnt,
                                             box_reg, proposals, out);
}

// Round 11
// 227.945 us; speedup vs baseline: 1.1391x; 1.0509x over previous
//
#include <hip/hip_runtime.h>
#include <math.h>

#define BB   16
#define RR   4096
#define NC   80          // foreground classes
#define KK   300
#define DD   100
#define CCAP 512         // per-(image,class) candidate cap (expected ~118, sigma ~11)
#define CAP  16384       // per-image kept-candidate cap (expected ~8800)
#define LCAP 48          // per-(block,class) local cap in kernel A
#define NW   5           // 5*64 = 320 >= KK bitmask words
#define PAD  (NW * 64)   // 320 padded rank slots
#define TPB  4           // nms tasks (waves) per block
#define HBINS 1280       // topd histogram bins (used: 1128)
#define HPT   5          // bins per scan-thread (1280/256)
#define BIN0  0x7A99u    // (0x3D4CCCCD >> 15): bin of score==0.05f

typedef unsigned long long ull;

// wave-local "barrier": drain LDS ops + compiler memory fence (single-wave tasks)
__device__ __forceinline__ void wsync() {
    asm volatile("s_waitcnt lgkmcnt(0)" ::: "memory");
}

__device__ __forceinline__ float4 decode_box(const float4 pr, const float4 rg) {
    float dx = rg.x / 10.0f;
    float dy = rg.y / 10.0f;
    float dw = fminf(rg.z / 5.0f, 4.135166556742356f);
    float dh = fminf(rg.w / 5.0f, 4.135166556742356f);
    float w  = pr.z - pr.x + 1.0f;
    float h  = pr.w - pr.y + 1.0f;
    float cx = pr.x + 0.5f * w;
    float cy = pr.y + 0.5f * h;
    float pcx = dx * w + cx;
    float pcy = dy * h + cy;
    float pw  = expf(dw) * w;
    float ph  = expf(dh) * h;
    float x1 = pcx - 0.5f * pw;
    float y1 = pcy - 0.5f * ph;
    float x2 = pcx + 0.5f * pw - 1.0f;
    float y2 = pcy + 0.5f * ph - 1.0f;
    x1 = fminf(fmaxf(x1, 0.0f), 1332.0f);
    y1 = fminf(fmaxf(y1, 0.0f), 799.0f);
    x2 = fminf(fmaxf(x2, 0.0f), 1332.0f);
    y2 = fminf(fmaxf(y2, 0.0f), 799.0f);
    return make_float4(x1, y1, x2, y2);
}

// ---- Kernel A: LDS-staged coalesced softmax + block-aggregated candidate emit ----
__global__ __launch_bounds__(256) void softmax_cand_kernel(
        const float* __restrict__ logits,
        ull*         __restrict__ cand2,     // [BB*NC][CCAP]
        int*         __restrict__ cls_cnt) { // [BB*NC]
    __shared__ float tile[256 * 81];
    __shared__ ull   lbuf[NC * LCAP];
    __shared__ int   lhist[NC];
    __shared__ int   gbase[NC];

    const int tid  = threadIdx.x;
    const int row0 = blockIdx.x * 256;
    const int b    = blockIdx.x >> 4;

    for (int i = tid; i < NC; i += 256) lhist[i] = 0;

    const float4* src = (const float4*)(logits + (size_t)row0 * 81);
    float4*       dst = (float4*)tile;
    for (int i = tid; i < 5184; i += 256) dst[i] = src[i];
    __syncthreads();

    float v[81];
    #pragma unroll
    for (int c = 0; c < 81; ++c) v[c] = tile[tid * 81 + c];

    float m = -1e30f;
    #pragma unroll
    for (int c = 0; c < 81; ++c) m = fmaxf(m, v[c]);

    float s = 0.0f;
    #pragma unroll
    for (int c = 0; c < 81; ++c) { float e = expf(v[c] - m); v[c] = e; s += e; }

    const unsigned rlow = (unsigned)((row0 + tid) & 4095);
    #pragma unroll
    for (int c = 1; c < 81; ++c) {
        float p = v[c] / s;
        if (p > 0.05f) {
            int ci  = c - 1;
            int pos = atomicAdd(&lhist[ci], 1);
            if (pos < LCAP)
                lbuf[ci * LCAP + pos] =
                    ((ull)__float_as_uint(p) << 32) | (unsigned)(~rlow);
        }
    }
    __syncthreads();

    if (tid < NC) {
        int h = lhist[tid]; if (h > LCAP) h = LCAP;
        gbase[tid] = atomicAdd(&cls_cnt[b * NC + tid], h);
    }
    __syncthreads();

    for (int idx = tid; idx < NC * LCAP; idx += 256) {
        int ci = idx / LCAP, j = idx - ci * LCAP;
        int h  = lhist[ci]; if (h > LCAP) h = LCAP;
        if (j < h) {
            int pos = gbase[ci] + j;
            if (pos < CCAP)
                cand2[(size_t)(b * NC + ci) * CCAP + pos] = lbuf[idx];
        }
    }
}

// ---- Kernel B1: per (image,class) sort + WIDE decode (20 waves/CU of MLP) ----
__global__ __launch_bounds__(256) void sortdec_kernel(
        ull*         __restrict__ cand2,      // in/out: sorted in place
        const int*   __restrict__ cls_cnt,
        const float* __restrict__ box_reg,
        const float* __restrict__ proposals,
        float4*      __restrict__ sboxes,     // [1280][PAD] rank-ordered
        float*       __restrict__ sarea) {    // [1280][PAD]
    #pragma clang fp contract(off)
    __shared__ ull k[CCAP];

    const int bid = blockIdx.x;     // 0..1279
    const int b   = bid / NC;
    const int ci  = bid % NC;
    const int tid = threadIdx.x;

    int M = cls_cnt[bid]; if (M > CCAP) M = CCAP;

    for (int i = tid; i < CCAP; i += 256)
        k[i] = (i < M) ? cand2[(size_t)bid * CCAP + i] : 0ULL;
    __syncthreads();

    for (int kk = 2; kk <= CCAP; kk <<= 1) {
        for (int j = kk >> 1; j > 0; j >>= 1) {
            for (int i = tid; i < CCAP; i += 256) {
                int ixj = i ^ j;
                if (ixj > i) {
                    bool desc = ((i & kk) == 0);
                    ull a = k[i], c = k[ixj];
                    if (desc ? (a < c) : (a > c)) { k[i] = c; k[ixj] = a; }
                }
            }
            __syncthreads();
        }
    }

    const int N = (M < KK) ? M : KK;

    // wide gather+decode: ranks 0..N-1 (high occupancy -> high MLP)
    for (int k2 = tid; k2 < PAD; k2 += 256) {
        if (k2 < N) {
            unsigned r = ~(unsigned)(k[k2] & 0xFFFFFFFFu);
            size_t n = (size_t)b * RR + r;
            const float4 pr = *(const float4*)(proposals + n * 4);
            const float4 rg = *(const float4*)(box_reg + n * 324 + (size_t)(ci + 1) * 4);
            float4 bb = decode_box(pr, rg);
            sboxes[(size_t)bid * PAD + k2] = bb;
            sarea[(size_t)bid * PAD + k2] = (bb.z - bb.x + 1.0f) * (bb.w - bb.y + 1.0f);
        } else {
            sboxes[(size_t)bid * PAD + k2] = make_float4(0.0f, 0.0f, 0.0f, 0.0f);
            sarea[(size_t)bid * PAD + k2] = 0.0f;
        }
    }
    // write back sorted keys (B2 reads them for append)
    for (int i = tid; i < CCAP; i += 256)
        cand2[(size_t)bid * CCAP + i] = k[i];
}

// ---- Kernel B2: 4 waves/block, ONE WAVE per (image,class): bitmask NMS + append ----
__global__ __launch_bounds__(256) void nms_kernel(
        const ull*    __restrict__ cand2,     // sorted keys
        const int*    __restrict__ cls_cnt,
        const float4* __restrict__ sboxes,
        const float*  __restrict__ sarea,
        ull*          __restrict__ img_keys,  // [BB][CAP]
        unsigned*     __restrict__ img_meta,  // [BB][CAP]  (ci<<12 | r)
        int*          __restrict__ g_cnt) {   // [BB]
    #pragma clang fp contract(off)
    __shared__ float bx1[TPB][PAD], by1[TPB][PAD],
                     bx2[TPB][PAD], by2[TPB][PAD], bar[TPB][PAD];

    const int wave = threadIdx.x >> 6;
    const int lane = threadIdx.x & 63;
    const int bid  = blockIdx.x * TPB + wave;   // 0..1279
    const int b    = bid / NC;
    const int ci   = bid % NC;

    int M = cls_cnt[bid]; if (M > CCAP) M = CCAP;
    const int N = (M < KK) ? M : KK;

    // coalesced load of rank-ordered boxes (L2-warm, contiguous)
    for (int k2 = lane; k2 < PAD; k2 += 64) {
        float4 bb = sboxes[(size_t)bid * PAD + k2];
        bx1[wave][k2] = bb.x; by1[wave][k2] = bb.y;
        bx2[wave][k2] = bb.z; by2[wave][k2] = bb.w;
        bar[wave][k2] = sarea[(size_t)bid * PAD + k2];
    }
    wsync();

    ull keepw[NW];
    #pragma unroll
    for (int w = 0; w < NW; ++w) {
        int lo = w * 64;
        keepw[w] = (N >= lo + 64) ? ~0ULL : (N <= lo ? 0ULL : ((1ULL << (N - lo)) - 1ULL));
    }

    #pragma unroll
    for (int t = 0; t < NW; ++t) {
        if (t * 64 >= N) break;
        const int i = t * 64 + lane;
        const float ax1 = bx1[wave][i], ay1 = by1[wave][i],
                    ax2 = bx2[wave][i], ay2 = by2[wave][i], aar = bar[wave][i];
        ull sup[NW];
        #pragma unroll
        for (int w = 0; w < NW; ++w) {
            ull mword = 0ULL;
            if (w >= t && w * 64 < N) {
                int jlo = w * 64; if (jlo < i + 1) jlo = i + 1;
                int jhi = w * 64 + 64; if (jhi > N) jhi = N;
                for (int j = jlo; j < jhi; ++j) {
                    float ltx = fmaxf(ax1, bx1[wave][j]);
                    float lty = fmaxf(ay1, by1[wave][j]);
                    float rbx = fminf(ax2, bx2[wave][j]);
                    float rby = fminf(ay2, by2[wave][j]);
                    float iw  = fmaxf(rbx - ltx + 1.0f, 0.0f);
                    float ih  = fmaxf(rby - lty + 1.0f, 0.0f);
                    float inter = iw * ih;
                    float iou   = inter / ((aar + bar[wave][j]) - inter);
                    if (iou > 0.5f) mword |= 1ULL << (j - w * 64);
                }
            }
            sup[w] = mword;
        }
        ull rowany = 0ULL;
        #pragma unroll
        for (int w = 0; w < NW; ++w) rowany |= sup[w];
        const ull act = __ballot(rowany != 0ULL);

        ull mloop = keepw[t] & act;
        while (mloop) {
            int l = __builtin_ctzll(mloop);
            if ((keepw[t] >> l) & 1ULL) {
                #pragma unroll
                for (int w = 0; w < NW; ++w) {
                    if (w >= t && w * 64 < N)
                        keepw[w] &= ~__shfl(sup[w], l);
                }
            }
            ull below = (l >= 63) ? ~0ULL : ((1ULL << (l + 1)) - 1ULL);
            mloop = keepw[t] & act & ~below;
        }
    }

    int total = 0;
    #pragma unroll
    for (int w = 0; w < NW; ++w) total += __popcll(keepw[w]);
    int base0 = 0;
    if (lane == 0) base0 = atomicAdd(&g_cnt[b], total);
    base0 = __shfl(base0, 0);

    int acc = 0;
    #pragma unroll
    for (int w = 0; w < NW; ++w) {
        if (w * 64 < N) {
            const ull km = keepw[w];
            const int k2 = w * 64 + lane;
            if ((km >> lane) & 1ULL) {
                int rank = __popcll(km & ((1ULL << lane) - 1ULL));
                int pos  = base0 + acc + rank;
                if (pos < CAP) {
                    ull key = cand2[(size_t)bid * CCAP + k2];   // sorted keys, small hot region
                    unsigned r  = ~(unsigned)(key & 0xFFFFFFFFu);
                    unsigned fi = (unsigned)(ci * KK + k2);
                    img_keys[(size_t)b * CAP + pos] =
                        (key & 0xFFFFFFFF00000000ULL) | (unsigned)(~fi);
                    img_meta[(size_t)b * CAP + pos] = ((unsigned)ci << 12) | (r & 4095u);
                }
            }
            acc += __popcll(km);
        }
    }
}

// ---- Kernel C: histogram select + single-wave register sort + emit (R8 verbatim) ----
__global__ __launch_bounds__(1024) void topd_kernel(
        const ull*      __restrict__ img_keys,
        const unsigned* __restrict__ img_meta,
        const int*      __restrict__ g_cnt,
        const float*    __restrict__ box_reg,
        const float*    __restrict__ proposals,
        float*          __restrict__ out) {
    __shared__ int  hist[HBINS];
    __shared__ int  suf[256];
    __shared__ ull  pk[256];
    __shared__ int  ps[256];
    __shared__ int  sh_cnt, sh_tb;

    const int b   = blockIdx.x;
    const int tid = threadIdx.x;
    int M = g_cnt[b]; if (M > CAP) M = CAP;
    const ull* kp = img_keys + (size_t)b * CAP;

    for (int i = tid; i < HBINS; i += 1024) hist[i] = 0;
    if (tid == 0) { sh_cnt = 0; sh_tb = 0; }
    __syncthreads();

    for (int i = tid; i < M; i += 1024) {
        unsigned k = (unsigned)(kp[i] >> 32);
        int bin = (int)((k >> 15) - BIN0);
        bin = (bin < 0) ? 0 : (bin >= HBINS ? HBINS - 1 : bin);
        atomicAdd(&hist[bin], 1);
    }
    __syncthreads();

    int tot = 0;
    if (tid < 256) {
        #pragma unroll
        for (int r = 0; r < HPT; ++r) tot += hist[tid * HPT + r];
        suf[tid] = tot;
    }
    __syncthreads();
    for (int off = 1; off < 256; off <<= 1) {
        int add = 0;
        if (tid < 256 && tid + off < 256) add = suf[tid + off];
        __syncthreads();
        if (tid < 256) suf[tid] += add;
        __syncthreads();
    }
    if (tid < 256) {
        int cum = suf[tid] - tot;
        #pragma unroll
        for (int jj = HPT - 1; jj >= 0; --jj) {
            int j    = tid * HPT + jj;
            int prev = cum;
            cum += hist[j];
            if (cum >= DD && prev < DD) sh_tb = j;
        }
    }
    __syncthreads();
    const unsigned keyLo = ((unsigned)sh_tb + BIN0) << 15;

    for (int i = tid; i < M; i += 1024) {
        ull key = kp[i];
        if ((unsigned)(key >> 32) >= keyLo) {
            int p = atomicAdd(&sh_cnt, 1);
            if (p < 256) { pk[p] = key; ps[p] = i; }
        }
    }
    __syncthreads();

    if (tid < 64) {
        const int lane  = tid;
        int ngath = sh_cnt; if (ngath > 256) ngath = 256;

        ull k4[4]; int s4[4];
        #pragma unroll
        for (int q = 0; q < 4; ++q) {
            int i = lane + 64 * q;
            bool vld = (i < ngath);
            k4[q] = vld ? pk[i] : 0ULL;
            s4[q] = vld ? ps[i] : -1;
        }

        #pragma unroll
        for (int k = 2; k <= 256; k <<= 1) {
            #pragma unroll
            for (int j = k >> 1; j > 0; j >>= 1) {
                if (j >= 64) {
                    const int qj = j >> 6;
                    #pragma unroll
                    for (int q = 0; q < 4; ++q) {
                        if ((q & qj) == 0 && (q + qj) < 4) {
                            int i0 = lane + 64 * q;
                            bool desc = ((i0 & k) == 0);
                            ull x = k4[q], y = k4[q + qj];
                            bool sw = desc ? (x < y) : (x > y);
                            if (sw) {
                                k4[q] = y; k4[q + qj] = x;
                                int t = s4[q]; s4[q] = s4[q + qj]; s4[q + qj] = t;
                            }
                        }
                    }
                } else {
                    #pragma unroll
                    for (int q = 0; q < 4; ++q) {
                        int i0 = lane + 64 * q;
                        bool desc  = ((i0 & k) == 0);
                        bool lower = ((lane & j) == 0);
                        ull pv = __shfl_xor(k4[q], j);
                        int sv = __shfl_xor(s4[q], j);
                        bool take = (desc == lower) ? (pv > k4[q]) : (pv < k4[q]);
                        if (take) { k4[q] = pv; s4[q] = sv; }
                    }
                }
            }
        }

        #pragma unroll
        for (int q = 0; q < 2; ++q) {
            int p = lane + 64 * q;
            if (p < DD) {
                float s; float4 bb; int label;
                if (p < ngath) {
                    ull key = k4[q];
                    unsigned fi   = ~(unsigned)(key & 0xFFFFFFFFu);
                    unsigned meta = img_meta[(size_t)b * CAP + s4[q]];
                    unsigned rr   = meta & 4095u;
                    unsigned ci   = meta >> 12;
                    s  = __uint_as_float((unsigned)(key >> 32));
                    size_t n = (size_t)b * RR + rr;
                    const float4 pr = *(const float4*)(proposals + n * 4);
                    const float4 rg = *(const float4*)(box_reg + n * 324 + (size_t)(ci + 1) * 4);
                    bb = decode_box(pr, rg);
                    label = (int)(fi / KK) + 1;
                } else {
                    s = -1.0f; bb = make_float4(0.0f, 0.0f, 0.0f, 0.0f); label = 0;
                }
                *(float4*)(out + (size_t)(b * DD + p) * 4) = bb;
                out[(size_t)BB * DD * 4 + b * DD + p] = s;
                out[(size_t)BB * DD * 4 + BB * DD + b * DD + p] = (float)label;
            }
        }
    }
}

extern "C" void kernel_launch(void* const* d_in, const int* in_sizes, int n_in,
                              void* d_out, int out_size, void* d_ws, size_t ws_size,
                              hipStream_t stream) {
    const float* logits    = (const float*)d_in[0];   // [B*R, 81]
    const float* box_reg   = (const float*)d_in[1];   // [B*R, 324]
    const float* proposals = (const float*)d_in[2];   // [B*R, 4]
    float* out = (float*)d_out;

    char* ws = (char*)d_ws;
    int*      cls_cnt  = (int*)ws;                    //      5,120 B
    int*      g_cnt    = (int*)(ws + 5120);           //         64 B
    ull*      cand2    = (ull*)(ws + 5184);           //  5,242,880 B
    float4*   sboxes   = (float4*)(ws + 5248064);     //  6,553,600 B (1280*320*16)
    float*    sarea    = (float*)(ws + 11801664);     //  1,638,400 B
    ull*      img_keys = (ull*)(ws + 13440064);       //  2,097,152 B
    unsigned* img_meta = (unsigned*)(ws + 15537216);  //  1,048,576 B

    hipMemsetAsync(ws, 0, 5184, stream);
    softmax_cand_kernel<<<(BB * RR) / 256, 256, 0, stream>>>(logits, cand2, cls_cnt);
    sortdec_kernel<<<BB * NC, 256, 0, stream>>>(cand2, cls_cnt, box_reg, proposals,
                                                sboxes, sarea);
    nms_kernel<<<(BB * NC) / TPB, 256, 0, stream>>>(cand2, cls_cnt, sboxes, sarea,
                                                    img_keys, img_meta, g_cnt);
    topd_kernel<<<BB, 1024, 0, stream>>>(img_keys, img_meta, g_cnt,
                                         box_reg, proposals, out);
}

// Round 12
// 218.175 us; speedup vs baseline: 1.1901x; 1.0448x over previous
//
#include <hip/hip_runtime.h>
#include <math.h>

#define BB   16
#define RR   4096
#define NC   80          // foreground classes
#define KK   300
#define DD   100
#define CCAP 512         // per-(image,class) candidate cap (expected ~118, sigma ~11)
#define CAP  16384       // per-image kept-candidate cap (expected ~8800)
#define LCAP 48          // per-(block,class) local cap in kernel A
#define NW   5           // 5*64 = 320 >= KK bitmask words
#define PAD  (NW * 64)   // 320 padded rank slots
#define TPB  4           // nms tasks (waves) per block
#define HBINS 1280       // score histogram bins (used: 1128)
#define HPT   5          // bins per scan-thread (1280/256)
#define BIN0  0x7A99u    // (0x3D4CCCCD >> 15): bin of score==0.05f

typedef unsigned long long ull;

// wave-local "barrier": drain LDS ops + compiler memory fence (single-wave tasks)
__device__ __forceinline__ void wsync() {
    asm volatile("s_waitcnt lgkmcnt(0)" ::: "memory");
}

__device__ __forceinline__ float4 decode_box(const float4 pr, const float4 rg) {
    float dx = rg.x / 10.0f;
    float dy = rg.y / 10.0f;
    float dw = fminf(rg.z / 5.0f, 4.135166556742356f);
    float dh = fminf(rg.w / 5.0f, 4.135166556742356f);
    float w  = pr.z - pr.x + 1.0f;
    float h  = pr.w - pr.y + 1.0f;
    float cx = pr.x + 0.5f * w;
    float cy = pr.y + 0.5f * h;
    float pcx = dx * w + cx;
    float pcy = dy * h + cy;
    float pw  = expf(dw) * w;
    float ph  = expf(dh) * h;
    float x1 = pcx - 0.5f * pw;
    float y1 = pcy - 0.5f * ph;
    float x2 = pcx + 0.5f * pw - 1.0f;
    float y2 = pcy + 0.5f * ph - 1.0f;
    x1 = fminf(fmaxf(x1, 0.0f), 1332.0f);
    y1 = fminf(fmaxf(y1, 0.0f), 799.0f);
    x2 = fminf(fmaxf(x2, 0.0f), 1332.0f);
    y2 = fminf(fmaxf(y2, 0.0f), 799.0f);
    return make_float4(x1, y1, x2, y2);
}

// ---- Kernel A: LDS-staged coalesced softmax + block-aggregated candidate emit ----
__global__ __launch_bounds__(256) void softmax_cand_kernel(
        const float* __restrict__ logits,
        ull*         __restrict__ cand2,     // [BB*NC][CCAP]
        int*         __restrict__ cls_cnt) { // [BB*NC]
    __shared__ float tile[256 * 81];
    __shared__ ull   lbuf[NC * LCAP];
    __shared__ int   lhist[NC];
    __shared__ int   gbase[NC];

    const int tid  = threadIdx.x;
    const int row0 = blockIdx.x * 256;
    const int b    = blockIdx.x >> 4;

    for (int i = tid; i < NC; i += 256) lhist[i] = 0;

    const float4* src = (const float4*)(logits + (size_t)row0 * 81);
    float4*       dst = (float4*)tile;
    for (int i = tid; i < 5184; i += 256) dst[i] = src[i];
    __syncthreads();

    float v[81];
    #pragma unroll
    for (int c = 0; c < 81; ++c) v[c] = tile[tid * 81 + c];

    float m = -1e30f;
    #pragma unroll
    for (int c = 0; c < 81; ++c) m = fmaxf(m, v[c]);

    float s = 0.0f;
    #pragma unroll
    for (int c = 0; c < 81; ++c) { float e = expf(v[c] - m); v[c] = e; s += e; }

    const unsigned rlow = (unsigned)((row0 + tid) & 4095);
    #pragma unroll
    for (int c = 1; c < 81; ++c) {
        float p = v[c] / s;
        if (p > 0.05f) {
            int ci  = c - 1;
            int pos = atomicAdd(&lhist[ci], 1);
            if (pos < LCAP)
                lbuf[ci * LCAP + pos] =
                    ((ull)__float_as_uint(p) << 32) | (unsigned)(~rlow);
        }
    }
    __syncthreads();

    if (tid < NC) {
        int h = lhist[tid]; if (h > LCAP) h = LCAP;
        gbase[tid] = atomicAdd(&cls_cnt[b * NC + tid], h);
    }
    __syncthreads();

    for (int idx = tid; idx < NC * LCAP; idx += 256) {
        int ci = idx / LCAP, j = idx - ci * LCAP;
        int h  = lhist[ci]; if (h > LCAP) h = LCAP;
        if (j < h) {
            int pos = gbase[ci] + j;
            if (pos < CCAP)
                cand2[(size_t)(b * NC + ci) * CCAP + pos] = lbuf[idx];
        }
    }
}

// ---- Kernel B1: per (image,class) ADAPTIVE sort + wide decode, N-bounded IO ----
__global__ __launch_bounds__(256) void sortdec_kernel(
        const ull*   __restrict__ cand2,
        const int*   __restrict__ cls_cnt,
        const float* __restrict__ box_reg,
        const float* __restrict__ proposals,
        float4*      __restrict__ sboxes,     // [1280][PAD] rank-ordered, [0,N) valid
        float*       __restrict__ sarea,      // [1280][PAD]
        uint2*       __restrict__ skeys) {    // [1280][PAD]  (score_bits, r)
    #pragma clang fp contract(off)
    __shared__ ull k[CCAP];

    const int bid = blockIdx.x;     // 0..1279
    const int b   = bid / NC;
    const int ci  = bid % NC;
    const int tid = threadIdx.x;

    int M = cls_cnt[bid]; if (M > CCAP) M = CCAP;
    int sortN = 2; while (sortN < M) sortN <<= 1;

    for (int i = tid; i < sortN; i += 256)
        k[i] = (i < M) ? cand2[(size_t)bid * CCAP + i] : 0ULL;
    __syncthreads();

    for (int kk = 2; kk <= sortN; kk <<= 1) {
        for (int j = kk >> 1; j > 0; j >>= 1) {
            for (int i = tid; i < sortN; i += 256) {
                int ixj = i ^ j;
                if (ixj > i) {
                    bool desc = ((i & kk) == 0);
                    ull a = k[i], c = k[ixj];
                    if (desc ? (a < c) : (a > c)) { k[i] = c; k[ixj] = a; }
                }
            }
            __syncthreads();
        }
    }

    const int N = (M < KK) ? M : KK;

    // wide gather+decode of ranks 0..N-1 only
    for (int k2 = tid; k2 < N; k2 += 256) {
        ull key = k[k2];
        unsigned sb = (unsigned)(key >> 32);
        unsigned r  = ~(unsigned)(key & 0xFFFFFFFFu);
        size_t n = (size_t)b * RR + r;
        const float4 pr = *(const float4*)(proposals + n * 4);
        const float4 rg = *(const float4*)(box_reg + n * 324 + (size_t)(ci + 1) * 4);
        float4 bb = decode_box(pr, rg);
        sboxes[(size_t)bid * PAD + k2] = bb;
        sarea[(size_t)bid * PAD + k2] = (bb.z - bb.x + 1.0f) * (bb.w - bb.y + 1.0f);
        skeys[(size_t)bid * PAD + k2] = make_uint2(sb, r);
    }
}

// ---- Kernel B2: 4 waves/block, ONE WAVE per (image,class): NMS + append + hist ----
__global__ __launch_bounds__(256) void nms_kernel(
        const int*    __restrict__ cls_cnt,
        const float4* __restrict__ sboxes,
        const float*  __restrict__ sarea,
        const uint2*  __restrict__ skeys,
        ull*          __restrict__ img_keys,  // [BB][CAP]
        unsigned*     __restrict__ img_meta,  // [BB][CAP]  (ci<<12 | r)
        int*          __restrict__ g_cnt,     // [BB]
        int*          __restrict__ g_hist) {  // [BB][HBINS]
    #pragma clang fp contract(off)
    __shared__ float bx1[TPB][PAD], by1[TPB][PAD],
                     bx2[TPB][PAD], by2[TPB][PAD], bar[TPB][PAD];

    const int wave = threadIdx.x >> 6;
    const int lane = threadIdx.x & 63;
    const int bid  = blockIdx.x * TPB + wave;   // 0..1279
    const int b    = bid / NC;
    const int ci   = bid % NC;

    int M = cls_cnt[bid]; if (M > CCAP) M = CCAP;
    const int N = (M < KK) ? M : KK;

    // coalesced load of rank-ordered boxes (only [0,N) is ever read by NMS)
    for (int k2 = lane; k2 < N; k2 += 64) {
        float4 bb = sboxes[(size_t)bid * PAD + k2];
        bx1[wave][k2] = bb.x; by1[wave][k2] = bb.y;
        bx2[wave][k2] = bb.z; by2[wave][k2] = bb.w;
        bar[wave][k2] = sarea[(size_t)bid * PAD + k2];
    }
    wsync();

    ull keepw[NW];
    #pragma unroll
    for (int w = 0; w < NW; ++w) {
        int lo = w * 64;
        keepw[w] = (N >= lo + 64) ? ~0ULL : (N <= lo ? 0ULL : ((1ULL << (N - lo)) - 1ULL));
    }

    #pragma unroll
    for (int t = 0; t < NW; ++t) {
        if (t * 64 >= N) break;
        const int i = t * 64 + lane;
        // lanes with i >= N read stale LDS; their sup rows are never consumed
        const float ax1 = bx1[wave][i], ay1 = by1[wave][i],
                    ax2 = bx2[wave][i], ay2 = by2[wave][i], aar = bar[wave][i];
        ull sup[NW];
        #pragma unroll
        for (int w = 0; w < NW; ++w) {
            ull mword = 0ULL;
            if (w >= t && w * 64 < N) {
                int jlo = w * 64; if (jlo < i + 1) jlo = i + 1;
                int jhi = w * 64 + 64; if (jhi > N) jhi = N;
                for (int j = jlo; j < jhi; ++j) {
                    float ltx = fmaxf(ax1, bx1[wave][j]);
                    float lty = fmaxf(ay1, by1[wave][j]);
                    float rbx = fminf(ax2, bx2[wave][j]);
                    float rby = fminf(ay2, by2[wave][j]);
                    float iw  = fmaxf(rbx - ltx + 1.0f, 0.0f);
                    float ih  = fmaxf(rby - lty + 1.0f, 0.0f);
                    float inter = iw * ih;
                    float iou   = inter / ((aar + bar[wave][j]) - inter);
                    if (iou > 0.5f) mword |= 1ULL << (j - w * 64);
                }
            }
            sup[w] = mword;
        }
        ull rowany = 0ULL;
        #pragma unroll
        for (int w = 0; w < NW; ++w) rowany |= sup[w];
        const ull act = __ballot(rowany != 0ULL);

        ull mloop = keepw[t] & act;
        while (mloop) {
            int l = __builtin_ctzll(mloop);
            if ((keepw[t] >> l) & 1ULL) {
                #pragma unroll
                for (int w = 0; w < NW; ++w) {
                    if (w >= t && w * 64 < N)
                        keepw[w] &= ~__shfl(sup[w], l);
                }
            }
            ull below = (l >= 63) ? ~0ULL : ((1ULL << (l + 1)) - 1ULL);
            mloop = keepw[t] & act & ~below;
        }
    }

    int total = 0;
    #pragma unroll
    for (int w = 0; w < NW; ++w) total += __popcll(keepw[w]);
    int base0 = 0;
    if (lane == 0) base0 = atomicAdd(&g_cnt[b], total);
    base0 = __shfl(base0, 0);

    int acc = 0;
    #pragma unroll
    for (int w = 0; w < NW; ++w) {
        if (w * 64 < N) {
            const ull km = keepw[w];
            const int k2 = w * 64 + lane;
            if ((km >> lane) & 1ULL) {
                int rank = __popcll(km & ((1ULL << lane) - 1ULL));
                int pos  = base0 + acc + rank;
                if (pos < CAP) {
                    uint2 sk = skeys[(size_t)bid * PAD + k2];   // (score_bits, r)
                    unsigned fi = (unsigned)(ci * KK + k2);
                    img_keys[(size_t)b * CAP + pos] =
                        ((ull)sk.x << 32) | (unsigned)(~fi);
                    img_meta[(size_t)b * CAP + pos] = ((unsigned)ci << 12) | (sk.y & 4095u);
                    int bin = (int)((sk.x >> 15) - BIN0);
                    bin = (bin < 0) ? 0 : (bin >= HBINS ? HBINS - 1 : bin);
                    atomicAdd(&g_hist[b * HBINS + bin], 1);
                }
            }
            acc += __popcll(km);
        }
    }
}

// ---- Kernel C: threshold from prebuilt hist + gather + wave sort + emit ----
__global__ __launch_bounds__(1024) void topd_kernel(
        const ull*      __restrict__ img_keys,
        const unsigned* __restrict__ img_meta,
        const int*      __restrict__ g_cnt,
        const int*      __restrict__ g_hist,
        const float*    __restrict__ box_reg,
        const float*    __restrict__ proposals,
        float*          __restrict__ out) {
    __shared__ int  suf[256];
    __shared__ ull  pk[256];
    __shared__ int  ps[256];
    __shared__ int  sh_cnt, sh_tb;

    const int b   = blockIdx.x;
    const int tid = threadIdx.x;
    int M = g_cnt[b]; if (M > CAP) M = CAP;
    const ull* kp = img_keys + (size_t)b * CAP;
    const int* hh = g_hist + b * HBINS;

    if (tid == 0) { sh_cnt = 0; sh_tb = 0; }
    __syncthreads();

    int h[HPT], tot = 0;
    if (tid < 256) {
        #pragma unroll
        for (int r = 0; r < HPT; ++r) { h[r] = hh[tid * HPT + r]; tot += h[r]; }
        suf[tid] = tot;
    }
    __syncthreads();
    for (int off = 1; off < 256; off <<= 1) {
        int add = 0;
        if (tid < 256 && tid + off < 256) add = suf[tid + off];
        __syncthreads();
        if (tid < 256) suf[tid] += add;
        __syncthreads();
    }
    if (tid < 256) {
        int cum = suf[tid] - tot;
        #pragma unroll
        for (int jj = HPT - 1; jj >= 0; --jj) {
            int prev = cum;
            cum += h[jj];
            if (cum >= DD && prev < DD) sh_tb = tid * HPT + jj;
        }
    }
    __syncthreads();
    const unsigned keyLo = ((unsigned)sh_tb + BIN0) << 15;

    for (int i = tid; i < M; i += 1024) {
        ull key = kp[i];
        if ((unsigned)(key >> 32) >= keyLo) {
            int p = atomicAdd(&sh_cnt, 1);
            if (p < 256) { pk[p] = key; ps[p] = i; }
        }
    }
    __syncthreads();

    if (tid < 64) {
        const int lane  = tid;
        int ngath = sh_cnt; if (ngath > 256) ngath = 256;

        ull k4[4]; int s4[4];
        #pragma unroll
        for (int q = 0; q < 4; ++q) {
            int i = lane + 64 * q;
            bool vld = (i < ngath);
            k4[q] = vld ? pk[i] : 0ULL;
            s4[q] = vld ? ps[i] : -1;
        }

        #pragma unroll
        for (int k = 2; k <= 256; k <<= 1) {
            #pragma unroll
            for (int j = k >> 1; j > 0; j >>= 1) {
                if (j >= 64) {
                    const int qj = j >> 6;
                    #pragma unroll
                    for (int q = 0; q < 4; ++q) {
                        if ((q & qj) == 0 && (q + qj) < 4) {
                            int i0 = lane + 64 * q;
                            bool desc = ((i0 & k) == 0);
                            ull x = k4[q], y = k4[q + qj];
                            bool sw = desc ? (x < y) : (x > y);
                            if (sw) {
                                k4[q] = y; k4[q + qj] = x;
                                int t = s4[q]; s4[q] = s4[q + qj]; s4[q + qj] = t;
                            }
                        }
                    }
                } else {
                    #pragma unroll
                    for (int q = 0; q < 4; ++q) {
                        int i0 = lane + 64 * q;
                        bool desc  = ((i0 & k) == 0);
                        bool lower = ((lane & j) == 0);
                        ull pv = __shfl_xor(k4[q], j);
                        int sv = __shfl_xor(s4[q], j);
                        bool take = (desc == lower) ? (pv > k4[q]) : (pv < k4[q]);
                        if (take) { k4[q] = pv; s4[q] = sv; }
                    }
                }
            }
        }

        #pragma unroll
        for (int q = 0; q < 2; ++q) {
            int p = lane + 64 * q;
            if (p < DD) {
                float s; float4 bb; int label;
                if (p < ngath) {
                    ull key = k4[q];
                    unsigned fi   = ~(unsigned)(key & 0xFFFFFFFFu);
                    unsigned meta = img_meta[(size_t)b * CAP + s4[q]];
                    unsigned rr   = meta & 4095u;
                    unsigned ci   = meta >> 12;
                    s  = __uint_as_float((unsigned)(key >> 32));
                    size_t n = (size_t)b * RR + rr;
                    const float4 pr = *(const float4*)(proposals + n * 4);
                    const float4 rg = *(const float4*)(box_reg + n * 324 + (size_t)(ci + 1) * 4);
                    bb = decode_box(pr, rg);
                    label = (int)(fi / KK) + 1;
                } else {
                    s = -1.0f; bb = make_float4(0.0f, 0.0f, 0.0f, 0.0f); label = 0;
                }
                *(float4*)(out + (size_t)(b * DD + p) * 4) = bb;
                out[(size_t)BB * DD * 4 + b * DD + p] = s;
                out[(size_t)BB * DD * 4 + BB * DD + b * DD + p] = (float)label;
            }
        }
    }
}

extern "C" void kernel_launch(void* const* d_in, const int* in_sizes, int n_in,
                              void* d_out, int out_size, void* d_ws, size_t ws_size,
                              hipStream_t stream) {
    const float* logits    = (const float*)d_in[0];   // [B*R, 81]
    const float* box_reg   = (const float*)d_in[1];   // [B*R, 324]
    const float* proposals = (const float*)d_in[2];   // [B*R, 4]
    float* out = (float*)d_out;

    char* ws = (char*)d_ws;
    int*      cls_cnt  = (int*)ws;                    //      5,120 B
    int*      g_cnt    = (int*)(ws + 5120);           //         64 B
    int*      g_hist   = (int*)(ws + 5248);           //     81,920 B  (ends 87,168)
    ull*      cand2    = (ull*)(ws + 87168);          //  5,242,880 B
    float4*   sboxes   = (float4*)(ws + 5330048);     //  6,553,600 B
    float*    sarea    = (float*)(ws + 11883648);     //  1,638,400 B
    uint2*    skeys    = (uint2*)(ws + 13522048);     //  3,276,800 B
    ull*      img_keys = (ull*)(ws + 16798848);       //  2,097,152 B
    unsigned* img_meta = (unsigned*)(ws + 18896000);  //  1,048,576 B

    hipMemsetAsync(ws, 0, 87168, stream);             // counters + hist
    softmax_cand_kernel<<<(BB * RR) / 256, 256, 0, stream>>>(logits, cand2, cls_cnt);
    sortdec_kernel<<<BB * NC, 256, 0, stream>>>(cand2, cls_cnt, box_reg, proposals,
                                                sboxes, sarea, skeys);
    nms_kernel<<<(BB * NC) / TPB, 256, 0, stream>>>(cls_cnt, sboxes, sarea, skeys,
                                                    img_keys, img_meta, g_cnt, g_hist);
    topd_kernel<<<BB, 1024, 0, stream>>>(img_keys, img_meta, g_cnt, g_hist,
                                         box_reg, proposals, out);
}

// Round 13
// 208.703 us; speedup vs baseline: 1.2442x; 1.0454x over previous
//
#include <hip/hip_runtime.h>
#include <math.h>

#define BB   16
#define RR   4096
#define NC   80          // foreground classes
#define KK   300
#define DD   100
#define CCAP 512         // per-(image,class) candidate cap (expected ~118, sigma ~11)
#define CAP  16384       // per-image kept-candidate cap (expected ~8800)
#define LCAP 48          // per-(block,class) local cap in kernel A
#define NW   5           // 5*64 = 320 >= KK bitmask words
#define PAD  (NW * 64)   // 320 padded rank slots
#define HBINS 1280       // score histogram bins (used: 1128)
#define HPT   5          // bins per scan-thread (1280/256)
#define BIN0  0x7A99u    // (0x3D4CCCCD >> 15): bin of score==0.05f

typedef unsigned long long ull;

__device__ __forceinline__ float4 decode_box(const float4 pr, const float4 rg) {
    float dx = rg.x / 10.0f;
    float dy = rg.y / 10.0f;
    float dw = fminf(rg.z / 5.0f, 4.135166556742356f);
    float dh = fminf(rg.w / 5.0f, 4.135166556742356f);
    float w  = pr.z - pr.x + 1.0f;
    float h  = pr.w - pr.y + 1.0f;
    float cx = pr.x + 0.5f * w;
    float cy = pr.y + 0.5f * h;
    float pcx = dx * w + cx;
    float pcy = dy * h + cy;
    float pw  = expf(dw) * w;
    float ph  = expf(dh) * h;
    float x1 = pcx - 0.5f * pw;
    float y1 = pcy - 0.5f * ph;
    float x2 = pcx + 0.5f * pw - 1.0f;
    float y2 = pcy + 0.5f * ph - 1.0f;
    x1 = fminf(fmaxf(x1, 0.0f), 1332.0f);
    y1 = fminf(fmaxf(y1, 0.0f), 799.0f);
    x2 = fminf(fmaxf(x2, 0.0f), 1332.0f);
    y2 = fminf(fmaxf(y2, 0.0f), 799.0f);
    return make_float4(x1, y1, x2, y2);
}

// ---- Kernel A: LDS-staged coalesced softmax + block-aggregated candidate emit ----
__global__ __launch_bounds__(256) void softmax_cand_kernel(
        const float* __restrict__ logits,
        ull*         __restrict__ cand2,     // [BB*NC][CCAP]
        int*         __restrict__ cls_cnt) { // [BB*NC]
    __shared__ float tile[256 * 81];
    __shared__ ull   lbuf[NC * LCAP];
    __shared__ int   lhist[NC];
    __shared__ int   gbase[NC];

    const int tid  = threadIdx.x;
    const int row0 = blockIdx.x * 256;
    const int b    = blockIdx.x >> 4;

    for (int i = tid; i < NC; i += 256) lhist[i] = 0;

    const float4* src = (const float4*)(logits + (size_t)row0 * 81);
    float4*       dst = (float4*)tile;
    for (int i = tid; i < 5184; i += 256) dst[i] = src[i];
    __syncthreads();

    float v[81];
    #pragma unroll
    for (int c = 0; c < 81; ++c) v[c] = tile[tid * 81 + c];

    float m = -1e30f;
    #pragma unroll
    for (int c = 0; c < 81; ++c) m = fmaxf(m, v[c]);

    float s = 0.0f;
    #pragma unroll
    for (int c = 0; c < 81; ++c) { float e = expf(v[c] - m); v[c] = e; s += e; }

    const unsigned rlow = (unsigned)((row0 + tid) & 4095);
    #pragma unroll
    for (int c = 1; c < 81; ++c) {
        float p = v[c] / s;
        if (p > 0.05f) {
            int ci  = c - 1;
            int pos = atomicAdd(&lhist[ci], 1);
            if (pos < LCAP)
                lbuf[ci * LCAP + pos] =
                    ((ull)__float_as_uint(p) << 32) | (unsigned)(~rlow);
        }
    }
    __syncthreads();

    if (tid < NC) {
        int h = lhist[tid]; if (h > LCAP) h = LCAP;
        gbase[tid] = atomicAdd(&cls_cnt[b * NC + tid], h);
    }
    __syncthreads();

    for (int idx = tid; idx < NC * LCAP; idx += 256) {
        int ci = idx / LCAP, j = idx - ci * LCAP;
        int h  = lhist[ci]; if (h > LCAP) h = LCAP;
        if (j < h) {
            int pos = gbase[ci] + j;
            if (pos < CCAP)
                cand2[(size_t)(b * NC + ci) * CCAP + pos] = lbuf[idx];
        }
    }
}

// ---- Kernel B: ONE BLOCK per (image,class): sort + wide decode + NMS + append ----
__global__ __launch_bounds__(256) void percls_kernel(
        const ull*   __restrict__ cand2,
        const int*   __restrict__ cls_cnt,
        const float* __restrict__ box_reg,
        const float* __restrict__ proposals,
        ull*         __restrict__ img_keys,  // [BB][CAP]
        unsigned*    __restrict__ img_meta,  // [BB][CAP]  (ci<<12 | r)
        int*         __restrict__ g_cnt,     // [BB]
        int*         __restrict__ g_hist) {  // [BB][HBINS]
    #pragma clang fp contract(off)
    __shared__ ull   keys[CCAP];                       // 4 KB (sorted keys)
    __shared__ float bx1[PAD], by1[PAD], bx2[PAD], by2[PAD], bar[PAD];  // 6.4 KB

    const int bid = blockIdx.x;     // 0..1279
    const int b   = bid / NC;
    const int ci  = bid % NC;
    const int tid = threadIdx.x;

    int M = cls_cnt[bid]; if (M > CCAP) M = CCAP;
    int sortN = 2; while (sortN < M) sortN <<= 1;

    for (int i = tid; i < sortN; i += 256)
        keys[i] = (i < M) ? cand2[(size_t)bid * CCAP + i] : 0ULL;
    __syncthreads();

    // adaptive bitonic sort, descending (identical key order to prior rounds)
    for (int kk = 2; kk <= sortN; kk <<= 1) {
        for (int j = kk >> 1; j > 0; j >>= 1) {
            for (int i = tid; i < sortN; i += 256) {
                int ixj = i ^ j;
                if (ixj > i) {
                    bool desc = ((i & kk) == 0);
                    ull a = keys[i], c = keys[ixj];
                    if (desc ? (a < c) : (a > c)) { keys[i] = c; keys[ixj] = a; }
                }
            }
            __syncthreads();
        }
    }

    const int N = (M < KK) ? M : KK;

    // wide gather+decode of ranks [0,N): 256 threads issue the random reads (MLP)
    for (int k2 = tid; k2 < N; k2 += 256) {
        unsigned r = ~(unsigned)(keys[k2] & 0xFFFFFFFFu);
        size_t n = (size_t)b * RR + r;
        const float4 pr = *(const float4*)(proposals + n * 4);
        const float4 rg = *(const float4*)(box_reg + n * 324 + (size_t)(ci + 1) * 4);
        float4 bb = decode_box(pr, rg);
        bx1[k2] = bb.x; by1[k2] = bb.y; bx2[k2] = bb.z; by2[k2] = bb.w;
        bar[k2] = (bb.z - bb.x + 1.0f) * (bb.w - bb.y + 1.0f);
    }
    __syncthreads();

    // ---- NMS + append: wave 0 only (proven R12 code path, LDS-sourced) ----
    if (tid < 64) {
        const int lane = tid;

        ull keepw[NW];
        #pragma unroll
        for (int w = 0; w < NW; ++w) {
            int lo = w * 64;
            keepw[w] = (N >= lo + 64) ? ~0ULL : (N <= lo ? 0ULL : ((1ULL << (N - lo)) - 1ULL));
        }

        #pragma unroll
        for (int t = 0; t < NW; ++t) {
            if (t * 64 >= N) break;
            const int i = t * 64 + lane;
            const float ax1 = bx1[i], ay1 = by1[i],
                        ax2 = bx2[i], ay2 = by2[i], aar = bar[i];
            ull sup[NW];
            #pragma unroll
            for (int w = 0; w < NW; ++w) {
                ull mword = 0ULL;
                if (w >= t && w * 64 < N) {
                    int jlo = w * 64; if (jlo < i + 1) jlo = i + 1;
                    int jhi = w * 64 + 64; if (jhi > N) jhi = N;
                    for (int j = jlo; j < jhi; ++j) {
                        float ltx = fmaxf(ax1, bx1[j]);
                        float lty = fmaxf(ay1, by1[j]);
                        float rbx = fminf(ax2, bx2[j]);
                        float rby = fminf(ay2, by2[j]);
                        float iw  = fmaxf(rbx - ltx + 1.0f, 0.0f);
                        float ih  = fmaxf(rby - lty + 1.0f, 0.0f);
                        float inter = iw * ih;
                        float iou   = inter / ((aar + bar[j]) - inter);
                        if (iou > 0.5f) mword |= 1ULL << (j - w * 64);
                    }
                }
                sup[w] = mword;
            }
            ull rowany = 0ULL;
            #pragma unroll
            for (int w = 0; w < NW; ++w) rowany |= sup[w];
            const ull act = __ballot(rowany != 0ULL);

            ull mloop = keepw[t] & act;
            while (mloop) {
                int l = __builtin_ctzll(mloop);
                if ((keepw[t] >> l) & 1ULL) {
                    #pragma unroll
                    for (int w = 0; w < NW; ++w) {
                        if (w >= t && w * 64 < N)
                            keepw[w] &= ~__shfl(sup[w], l);
                    }
                }
                ull below = (l >= 63) ? ~0ULL : ((1ULL << (l + 1)) - 1ULL);
                mloop = keepw[t] & act & ~below;
            }
        }

        int total = 0;
        #pragma unroll
        for (int w = 0; w < NW; ++w) total += __popcll(keepw[w]);
        int base0 = 0;
        if (lane == 0) base0 = atomicAdd(&g_cnt[b], total);
        base0 = __shfl(base0, 0);

        int acc = 0;
        #pragma unroll
        for (int w = 0; w < NW; ++w) {
            if (w * 64 < N) {
                const ull km = keepw[w];
                const int k2 = w * 64 + lane;
                if ((km >> lane) & 1ULL) {
                    int rank = __popcll(km & ((1ULL << lane) - 1ULL));
                    int pos  = base0 + acc + rank;
                    if (pos < CAP) {
                        ull key = keys[k2];
                        unsigned sb = (unsigned)(key >> 32);
                        unsigned r  = ~(unsigned)(key & 0xFFFFFFFFu);
                        unsigned fi = (unsigned)(ci * KK + k2);
                        img_keys[(size_t)b * CAP + pos] =
                            ((ull)sb << 32) | (unsigned)(~fi);
                        img_meta[(size_t)b * CAP + pos] = ((unsigned)ci << 12) | (r & 4095u);
                        int bin = (int)((sb >> 15) - BIN0);
                        bin = (bin < 0) ? 0 : (bin >= HBINS ? HBINS - 1 : bin);
                        atomicAdd(&g_hist[b * HBINS + bin], 1);
                    }
                }
                acc += __popcll(km);
            }
        }
    }
}

// ---- Kernel C: threshold from prebuilt hist + gather + wave sort + emit ----
__global__ __launch_bounds__(1024) void topd_kernel(
        const ull*      __restrict__ img_keys,
        const unsigned* __restrict__ img_meta,
        const int*      __restrict__ g_cnt,
        const int*      __restrict__ g_hist,
        const float*    __restrict__ box_reg,
        const float*    __restrict__ proposals,
        float*          __restrict__ out) {
    __shared__ int  suf[256];
    __shared__ ull  pk[256];
    __shared__ int  ps[256];
    __shared__ int  sh_cnt, sh_tb;

    const int b   = blockIdx.x;
    const int tid = threadIdx.x;
    int M = g_cnt[b]; if (M > CAP) M = CAP;
    const ull* kp = img_keys + (size_t)b * CAP;
    const int* hh = g_hist + b * HBINS;

    if (tid == 0) { sh_cnt = 0; sh_tb = 0; }
    __syncthreads();

    int h[HPT], tot = 0;
    if (tid < 256) {
        #pragma unroll
        for (int r = 0; r < HPT; ++r) { h[r] = hh[tid * HPT + r]; tot += h[r]; }
        suf[tid] = tot;
    }
    __syncthreads();
    for (int off = 1; off < 256; off <<= 1) {
        int add = 0;
        if (tid < 256 && tid + off < 256) add = suf[tid + off];
        __syncthreads();
        if (tid < 256) suf[tid] += add;
        __syncthreads();
    }
    if (tid < 256) {
        int cum = suf[tid] - tot;
        #pragma unroll
        for (int jj = HPT - 1; jj >= 0; --jj) {
            int prev = cum;
            cum += h[jj];
            if (cum >= DD && prev < DD) sh_tb = tid * HPT + jj;
        }
    }
    __syncthreads();
    const unsigned keyLo = ((unsigned)sh_tb + BIN0) << 15;

    for (int i = tid; i < M; i += 1024) {
        ull key = kp[i];
        if ((unsigned)(key >> 32) >= keyLo) {
            int p = atomicAdd(&sh_cnt, 1);
            if (p < 256) { pk[p] = key; ps[p] = i; }
        }
    }
    __syncthreads();

    if (tid < 64) {
        const int lane  = tid;
        int ngath = sh_cnt; if (ngath > 256) ngath = 256;

        ull k4[4]; int s4[4];
        #pragma unroll
        for (int q = 0; q < 4; ++q) {
            int i = lane + 64 * q;
            bool vld = (i < ngath);
            k4[q] = vld ? pk[i] : 0ULL;
            s4[q] = vld ? ps[i] : -1;
        }

        #pragma unroll
        for (int k = 2; k <= 256; k <<= 1) {
            #pragma unroll
            for (int j = k >> 1; j > 0; j >>= 1) {
                if (j >= 64) {
                    const int qj = j >> 6;
                    #pragma unroll
                    for (int q = 0; q < 4; ++q) {
                        if ((q & qj) == 0 && (q + qj) < 4) {
                            int i0 = lane + 64 * q;
                            bool desc = ((i0 & k) == 0);
                            ull x = k4[q], y = k4[q + qj];
                            bool sw = desc ? (x < y) : (x > y);
                            if (sw) {
                                k4[q] = y; k4[q + qj] = x;
                                int t = s4[q]; s4[q] = s4[q + qj]; s4[q + qj] = t;
                            }
                        }
                    }
                } else {
                    #pragma unroll
                    for (int q = 0; q < 4; ++q) {
                        int i0 = lane + 64 * q;
                        bool desc  = ((i0 & k) == 0);
                        bool lower = ((lane & j) == 0);
                        ull pv = __shfl_xor(k4[q], j);
                        int sv = __shfl_xor(s4[q], j);
                        bool take = (desc == lower) ? (pv > k4[q]) : (pv < k4[q]);
                        if (take) { k4[q] = pv; s4[q] = sv; }
                    }
                }
            }
        }

        #pragma unroll
        for (int q = 0; q < 2; ++q) {
            int p = lane + 64 * q;
            if (p < DD) {
                float s; float4 bb; int label;
                if (p < ngath) {
                    ull key = k4[q];
                    unsigned fi   = ~(unsigned)(key & 0xFFFFFFFFu);
                    unsigned meta = img_meta[(size_t)b * CAP + s4[q]];
                    unsigned rr   = meta & 4095u;
                    unsigned ci   = meta >> 12;
                    s  = __uint_as_float((unsigned)(key >> 32));
                    size_t n = (size_t)b * RR + rr;
                    const float4 pr = *(const float4*)(proposals + n * 4);
                    const float4 rg = *(const float4*)(box_reg + n * 324 + (size_t)(ci + 1) * 4);
                    bb = decode_box(pr, rg);
                    label = (int)(fi / KK) + 1;
                } else {
                    s = -1.0f; bb = make_float4(0.0f, 0.0f, 0.0f, 0.0f); label = 0;
                }
                *(float4*)(out + (size_t)(b * DD + p) * 4) = bb;
                out[(size_t)BB * DD * 4 + b * DD + p] = s;
                out[(size_t)BB * DD * 4 + BB * DD + b * DD + p] = (float)label;
            }
        }
    }
}

extern "C" void kernel_launch(void* const* d_in, const int* in_sizes, int n_in,
                              void* d_out, int out_size, void* d_ws, size_t ws_size,
                              hipStream_t stream) {
    const float* logits    = (const float*)d_in[0];   // [B*R, 81]
    const float* box_reg   = (const float*)d_in[1];   // [B*R, 324]
    const float* proposals = (const float*)d_in[2];   // [B*R, 4]
    float* out = (float*)d_out;

    char* ws = (char*)d_ws;
    int*      cls_cnt  = (int*)ws;                    //      5,120 B
    int*      g_cnt    = (int*)(ws + 5120);           //         64 B
    int*      g_hist   = (int*)(ws + 5248);           //     81,920 B  (ends 87,168)
    ull*      cand2    = (ull*)(ws + 87168);          //  5,242,880 B
    ull*      img_keys = (ull*)(ws + 5330048);        //  2,097,152 B
    unsigned* img_meta = (unsigned*)(ws + 7427200);   //  1,048,576 B

    hipMemsetAsync(ws, 0, 87168, stream);             // counters + hist
    softmax_cand_kernel<<<(BB * RR) / 256, 256, 0, stream>>>(logits, cand2, cls_cnt);
    percls_kernel<<<BB * NC, 256, 0, stream>>>(cand2, cls_cnt, box_reg, proposals,
                                               img_keys, img_meta, g_cnt, g_hist);
    topd_kernel<<<BB, 1024, 0, stream>>>(img_keys, img_meta, g_cnt, g_hist,
                                         box_reg, proposals, out);
}